// Round 2
// baseline (2815.987 us; speedup 1.0000x reference)
//
#include <hip/hip_runtime.h>

// ---- filter / neuron constants (double, matching the Python reference) ----
#define EMD 0.8824969025845955      // exp(-1/8)
#define ESD 0.6065306597126334      // exp(-1/2)
#define A1C ((float)(EMD + ESD))                    // y[t-1] coeff
#define A2C ((float)(-(EMD * ESD)))                 // y[t-2] coeff
#define BC  ((float)((8.0 / 6.0) * (EMD - ESD)))    // x[t] coeff (ETA=8/6)
#define EMF ((float)EMD)                            // reset decay

// B=64, T=300. Layers: 300 -> 500 -> 200 -> 500 -> 300.
//
// Exactness contract (absmax 0.0 through round 6): reference currents are a
// SEQUENTIAL ascending-i fp32 fold of W[o,i]*s[i]; spikes are exactly 0/1.
// Round 7 computes the fold DENSELY: acc = fmaf(sel_i, w_i, acc) for EVERY i
// ascending, sel_i in {0.0f, 1.0f} from the ballot bit. sel=1: fmaf(1,w,acc)
// == acc+w exactly. sel=0: fmaf(0,w,acc) == acc + (+/-0) == acc bitwise
// (acc never -0; w always staged finite -- K/O tails staged as 0.0f, so no
// 0*NaN/0*Inf). Same fold order => bitwise-identical currents.

// ---------------------------------------------------------------------------
// Generic batched transpose: src [Bt][R][C] -> dst [Bt][C][R]
// ---------------------------------------------------------------------------
__global__ __launch_bounds__(256) void transpose_rc(
    const float* __restrict__ src, float* __restrict__ dst, int R, int C)
{
    __shared__ float tile[32][33];
    const int c0 = blockIdx.x * 32;
    const int r0 = blockIdx.y * 32;
    const int b  = blockIdx.z;
    const float* S = src + (size_t)b * R * C;
    float* D = dst + (size_t)b * R * C;
    const int tx = threadIdx.x;      // 0..31
    const int ty = threadIdx.y;      // 0..7
#pragma unroll
    for (int s = 0; s < 4; s++) {
        const int r = r0 + ty + 8 * s;
        const int c = c0 + tx;
        if (r < R && c < C) tile[ty + 8 * s][tx] = S[(size_t)r * C + c];
    }
    __syncthreads();
#pragma unroll
    for (int s = 0; s < 4; s++) {
        const int c = c0 + ty + 8 * s;
        const int r = r0 + tx;
        if (c < C && r < R) D[(size_t)c * R + r] = tile[tx][ty + 8 * s];
    }
}

// ---------------------------------------------------------------------------
// Dense register-weight spike GEMM: C[b,t,o] = sum_i Wt[i,o] * S[b,t,i].
// S: [B,T,K] binary, Wt: [K,O], C: [B,T,O].
//
// Block: 256 thr (4 waves). o-chunk 128 (2 o's/lane), each wave owns 16 t's.
// K walked in 32-row chunks; per chunk each LANE holds the 32 float2 weights
// for its o-pair in VGPRs (64 VGPRs), loaded from a double-buffered 16KB LDS
// stage. Spike bits: one ballot per t-PAIR (lanes 0-31 carry t_even's 32 k's,
// lanes 32-63 t_odd's) -> wave-uniform 64-bit SGPR mask. Inner body per
// (t-pair, i): 2 s_bitcmp+s_cselect (SALU, parallel pipe) + 4 v_fmac reading
// the SGPR sel. No memory op, no wait in the inner loop; acc.x/.y pairs give
// the 2-way ILP that covers FMA dep latency exactly.
// ---------------------------------------------------------------------------
#define KG  32
#define OCN 128
#define TW  16          // t's per wave
#define TCN 64          // 4 waves * TW

__global__ __launch_bounds__(256, 2) void spmm_dense(
    const float* __restrict__ S, const float* __restrict__ Wt,
    float* __restrict__ C, int K, int O, int T)
{
    __shared__ float Wls[2][KG * OCN];   // 2 x 16 KB
    const int tid  = threadIdx.x;
    const int lane = tid & 63;
    const int wv   = tid >> 6;           // 0..3
    const int oc   = blockIdx.x * OCN;
    const int t0   = blockIdx.y * TCN + wv * TW;
    const int b    = blockIdx.z;

    const float* Sb = S + (size_t)b * T * K;
    float* Cb = C + (size_t)b * T * O;

    float2 acc[TW];
#pragma unroll
    for (int u = 0; u < TW; u++) acc[u] = make_float2(0.f, 0.f);

    const int nkc = (K + KG - 1) / KG;

    // ---- staging: 32 rows x 128 cols = 16 KB = 256 thr x 1 float4 x 4 iters
    float4 wpf[4];
#define LOADW(kc)                                                              \
    {                                                                          \
        const int kb_ = (kc) * KG;                                             \
        _Pragma("unroll")                                                      \
        for (int r = 0; r < 4; r++) {                                          \
            const int idx = r * 256 + tid;                                     \
            const int k = kb_ + (idx >> 5);                                    \
            const int o = oc + (idx & 31) * 4;                                 \
            float4 w = make_float4(0.f, 0.f, 0.f, 0.f);                        \
            if (k < K && o + 3 < O)                                            \
                w = *reinterpret_cast<const float4*>(&Wt[(size_t)k * O + o]);  \
            wpf[r] = w;                                                        \
        }                                                                      \
    }

#define STOREW(buf)                                                            \
    {                                                                          \
        _Pragma("unroll")                                                      \
        for (int r = 0; r < 4; r++) {                                          \
            const int idx = r * 256 + tid;                                     \
            *reinterpret_cast<float4*>(                                        \
                &Wls[buf][(idx >> 5) * OCN + (idx & 31) * 4]) = wpf[r];        \
        }                                                                      \
    }

    // ---- spike prefetch: lanes 0-31 carry t_even, lanes 32-63 t_odd
    float sv[TW / 2];
#define LOADS(kc)                                                              \
    {                                                                          \
        const int kk = (kc) * KG + (lane & 31);                                \
        _Pragma("unroll")                                                      \
        for (int p = 0; p < TW / 2; p++) {                                     \
            const int t = t0 + 2 * p + (lane >> 5);                            \
            sv[p] = (t < T && kk < K) ? Sb[(size_t)t * K + kk] : 0.0f;         \
        }                                                                      \
    }

    LOADW(0)
    LOADS(0)
    STOREW(0)
    __syncthreads();

    for (int kc = 0; kc < nkc; kc++) {
        const int cur = kc & 1;

        // masks first (consume sv before the prefetches overwrite it)
        unsigned long long mk[TW / 2];
#pragma unroll
        for (int p = 0; p < TW / 2; p++) mk[p] = __ballot(sv[p] != 0.0f);

        if (kc + 1 < nkc) {
            LOADW(kc + 1)       // global -> regs, lands during fma body
            LOADS(kc + 1)
        }

        // weight chunk LDS -> VGPRs (conflict-free: 512B consecutive / row)
        float2 wr[KG];
#pragma unroll
        for (int i = 0; i < KG; i++)
            wr[i] = *reinterpret_cast<const float2*>(&Wls[cur][i * OCN + 2 * lane]);

        // ---- dense fmac body: per t-pair p, ascending i
#pragma unroll
        for (int p = 0; p < TW / 2; p++) {
            const unsigned long long m = mk[p];
#pragma unroll
            for (int i = 0; i < KG; i++) {
                const float s0 = ((m >> i) & 1ull) ? 1.0f : 0.0f;        // t0+2p
                const float s1 = ((m >> (i + 32)) & 1ull) ? 1.0f : 0.0f; // t0+2p+1
                acc[2 * p].x     = fmaf(s0, wr[i].x, acc[2 * p].x);
                acc[2 * p].y     = fmaf(s0, wr[i].y, acc[2 * p].y);
                acc[2 * p + 1].x = fmaf(s1, wr[i].x, acc[2 * p + 1].x);
                acc[2 * p + 1].y = fmaf(s1, wr[i].y, acc[2 * p + 1].y);
            }
        }

        if (kc + 1 < nkc) {
            STOREW((kc + 1) & 1)   // writes the buffer all waves finished reading
            __syncthreads();
        }
    }

#pragma unroll
    for (int u = 0; u < TW; u++) {
        const int t = t0 + u;
        const int o = oc + lane * 2;
        if (t < T && o + 1 < O)               // O even -> pair all-or-nothing
            *reinterpret_cast<float2*>(&Cb[(size_t)t * O + o]) = acc[u];
    }
}

// ---------------------------------------------------------------------------
// LIF in time-major layout, in-place: C[b,t,o] currents -> spikes.
// One thread per (b,o); strided (stride O) column walk with 8-deep unrolled
// prefetch ring (constant indices -> stays in VGPRs). T fixed at 300.
// ---------------------------------------------------------------------------
#define LIF_STEP_S(xval, sval)                                                 \
    {                                                                          \
        const float y = A1 * y1 + A2 * y2 + Bc * (xval); y2 = y1; y1 = y;      \
        const float v = y + bi + r;                                            \
        sval = (v >= 1.0f) ? 1.0f : 0.0f;                                      \
        r = r * EMF - sval;                                                    \
    }

__global__ __launch_bounds__(64) void lif_t(
    float* __restrict__ C, const float* __restrict__ bias,
    const float* __restrict__ a1p, const float* __restrict__ a2p,
    const float* __restrict__ bp, int O)
{
    const int o = blockIdx.x * 64 + threadIdx.x;
    const int b = blockIdx.y;
    if (o >= O) return;
    const float A1 = a1p[0], A2 = a2p[0], Bc = bp[0];
    const float bi = bias[o];
    float* col = C + (size_t)b * 300 * O + o;

    float pf[8];
#pragma unroll
    for (int u = 0; u < 8; u++) pf[u] = col[(size_t)u * O];

    float y1 = 0.f, y2 = 0.f, r = 0.f;
    for (int blk = 0; blk < 37; blk++) {       // t = 0..295
#pragma unroll
        for (int u = 0; u < 8; u++) {
            const int t = blk * 8 + u;
            const float x = pf[u];
            if (t + 8 < 300) pf[u] = col[(size_t)(t + 8) * O];
            float s;
            LIF_STEP_S(x, s)
            col[(size_t)t * O] = s;
        }
    }
#pragma unroll
    for (int u = 0; u < 4; u++) {              // t = 296..299
        const float x = pf[u];
        float s;
        LIF_STEP_S(x, s)
        col[(size_t)(296 + u) * O] = s;
    }
}

// ---------------------------------------------------------------------------
// Layer-4 LIF + fixed output dual-exp IIR. C: currents->spikes (in place),
// F: filtered output. Both [B,T,O], O=300.
// ---------------------------------------------------------------------------
__global__ __launch_bounds__(64) void lif4_t(
    float* __restrict__ C, float* __restrict__ F,
    const float* __restrict__ bias,
    const float* __restrict__ a1p, const float* __restrict__ a2p,
    const float* __restrict__ bp, int O)
{
    const int o = blockIdx.x * 64 + threadIdx.x;
    const int b = blockIdx.y;
    if (o >= O) return;
    const float A1 = a1p[0], A2 = a2p[0], Bc = bp[0];
    const float bi = bias[o];
    float* col  = C + (size_t)b * 300 * O + o;
    float* fcol = F + (size_t)b * 300 * O + o;

    float pf[8];
#pragma unroll
    for (int u = 0; u < 8; u++) pf[u] = col[(size_t)u * O];

    float y1 = 0.f, y2 = 0.f, r = 0.f;
    float z1 = 0.f, z2 = 0.f;
    for (int blk = 0; blk < 37; blk++) {
#pragma unroll
        for (int u = 0; u < 8; u++) {
            const int t = blk * 8 + u;
            const float x = pf[u];
            if (t + 8 < 300) pf[u] = col[(size_t)(t + 8) * O];
            float s;
            LIF_STEP_S(x, s)
            const float z = A1C * z1 + A2C * z2 + BC * s; z2 = z1; z1 = z;
            col[(size_t)t * O]  = s;
            fcol[(size_t)t * O] = z;
        }
    }
#pragma unroll
    for (int u = 0; u < 4; u++) {
        const int t = 296 + u;
        const float x = pf[u];
        float s;
        LIF_STEP_S(x, s)
        const float z = A1C * z1 + A2C * z2 + BC * s; z2 = z1; z1 = z;
        col[(size_t)t * O]  = s;
        fcol[(size_t)t * O] = z;
    }
}

// ---------------------------------------------------------------------------
extern "C" void kernel_launch(void* const* d_in, const int* in_sizes, int n_in,
                              void* d_out, int out_size, void* d_ws, size_t ws_size,
                              hipStream_t stream)
{
    const float* inputs = (const float*)d_in[0];           // [64,300,300] binary
    const float* a1_1 = (const float*)d_in[1];
    const float* a2_1 = (const float*)d_in[2];
    const float* b_1  = (const float*)d_in[3];
    const float* W1   = (const float*)d_in[4];             // [500,300]
    const float* bias1= (const float*)d_in[5];
    const float* a1_2 = (const float*)d_in[6];
    const float* a2_2 = (const float*)d_in[7];
    const float* b_2  = (const float*)d_in[8];
    const float* W2   = (const float*)d_in[9];             // [200,500]
    const float* bias2= (const float*)d_in[10];
    const float* a1_3 = (const float*)d_in[11];
    const float* a2_3 = (const float*)d_in[12];
    const float* b_3  = (const float*)d_in[13];
    const float* W3   = (const float*)d_in[14];            // [500,200]
    const float* bias3= (const float*)d_in[15];
    const float* a1_4 = (const float*)d_in[16];
    const float* a2_4 = (const float*)d_in[17];
    const float* b_4  = (const float*)d_in[18];
    const float* W4   = (const float*)d_in[19];            // [300,500]
    const float* bias4= (const float*)d_in[20];

    const int B = 64, T = 300;

    // Workspace (proven size 53.76 MB): c1 = 9.6M floats, c2 = 3.84M floats.
    float* ws = (float*)d_ws;
    float* c1 = ws;                 // [B,T,500]; later filt_tmp [B,T,300]
    float* c2 = ws + 9600000;       // [B,T,200]

    // d_out regions double as scratch until the final transposes:
    // region1 [0..5.76M): Wt1..4 (500K floats), later final s4 [B,O,T]
    // region2 [5.76M..11.52M): inputT/c4/s4_tmp [B,T,300], later final filt
    float* out = (float*)d_out;
    float* reg1 = out;
    float* reg2 = out + 5760000;
    float* Wt1 = reg1;              // [300,500] = 150000
    float* Wt2 = reg1 + 150000;     // [500,200] = 100000
    float* Wt3 = reg1 + 250000;     // [200,500] = 100000
    float* Wt4 = reg1 + 350000;     // [500,300] = 150000

    const dim3 tb(32, 8);

    // Weight transposes W[O,K] -> Wt[K,O]
    transpose_rc<<<dim3(10, 16, 1), tb, 0, stream>>>(W1, Wt1, 500, 300);
    transpose_rc<<<dim3(16,  7, 1), tb, 0, stream>>>(W2, Wt2, 200, 500);
    transpose_rc<<<dim3( 7, 16, 1), tb, 0, stream>>>(W3, Wt3, 500, 200);
    transpose_rc<<<dim3(16, 10, 1), tb, 0, stream>>>(W4, Wt4, 300, 500);
    // Input spikes [B,IN,T] -> [B,T,IN]
    transpose_rc<<<dim3(10, 10, B), tb, 0, stream>>>(inputs, reg2, 300, 300);

    // t-blocks: ceil(300/64) = 5
    // Layer 1: 300 -> 500
    spmm_dense<<<dim3(4, 5, B), 256, 0, stream>>>(reg2, Wt1, c1, 300, 500, T);
    lif_t<<<dim3(8, B), 64, 0, stream>>>(c1, bias1, a1_1, a2_1, b_1, 500);
    // Layer 2: 500 -> 200
    spmm_dense<<<dim3(2, 5, B), 256, 0, stream>>>(c1, Wt2, c2, 500, 200, T);
    lif_t<<<dim3(4, B), 64, 0, stream>>>(c2, bias2, a1_2, a2_2, b_2, 200);
    // Layer 3: 200 -> 500 (write into c1; s1 dead)
    spmm_dense<<<dim3(4, 5, B), 256, 0, stream>>>(c2, Wt3, c1, 200, 500, T);
    lif_t<<<dim3(8, B), 64, 0, stream>>>(c1, bias3, a1_3, a2_3, b_3, 500);
    // Layer 4: 500 -> 300 into reg2 (inputT dead); LIF+filter, filt_tmp -> c1
    spmm_dense<<<dim3(3, 5, B), 256, 0, stream>>>(c1, Wt4, reg2, 500, 300, T);
    lif4_t<<<dim3(5, B), 64, 0, stream>>>(reg2, c1, bias4, a1_4, a2_4, b_4, 300);

    // Final transposes [B,T,O] -> [B,O,T]: s4 first (frees reg2), then filt.
    transpose_rc<<<dim3(10, 10, B), tb, 0, stream>>>(reg2, reg1, 300, 300);
    transpose_rc<<<dim3(10, 10, B), tb, 0, stream>>>(c1, reg2, 300, 300);
}

// Round 3
// 420.893 us; speedup vs baseline: 6.6905x; 6.6905x over previous
//
#include <hip/hip_runtime.h>

// ---- filter / neuron constants (double, matching the Python reference) ----
#define EMD 0.8824969025845955      // exp(-1/8)
#define ESD 0.6065306597126334      // exp(-1/2)
#define A1C ((float)(EMD + ESD))                    // y[t-1] coeff
#define A2C ((float)(-(EMD * ESD)))                 // y[t-2] coeff
#define BC  ((float)((8.0 / 6.0) * (EMD - ESD)))    // x[t] coeff (ETA=8/6)
#define EMF ((float)EMD)                            // reset decay

// B=64, T=300. Layers: 300 -> 500 -> 200 -> 500 -> 300.
//
// Exactness contract (absmax 0.0, rounds 1-5 structure): reference currents
// are a SEQUENTIAL ascending-i fp32 fold of W[o,i]*s[i]; spikes are exactly
// 0/1. Skipping s==0 terms is bitwise-neutral; processing set bits in
// ascending order is the SAME add sequence. Round 8: K chunks of 32; per t
// the 32-bit mask is walked ascending (lo ballot word = k 0..31 ascending,
// hi word = the paired t), chunks ascending -> identical fold per (t,o).
//
// History: r6 (VALU bit-extract pipeline) regressed 105->131us: >1 VALU op
// per accumulated float loses; the 2-adds/bit walk is the instruction floor.
// r7 (dense register-weight fmac) regressed 8x: weight array spilled to
// scratch (WRITE_SIZE 1.24GB) and dense work floor ~= sparse measured. This
// file restores the r5 walk; levers are occupancy (16KB LDS -> 8 blocks/CU
// vs 5) and cross-chunk spike prefetch (S-load latency was exposed per
// chunk between load and ballot).

// ---------------------------------------------------------------------------
// Generic batched transpose: src [Bt][R][C] -> dst [Bt][C][R]
// ---------------------------------------------------------------------------
__global__ __launch_bounds__(256) void transpose_rc(
    const float* __restrict__ src, float* __restrict__ dst, int R, int C)
{
    __shared__ float tile[32][33];
    const int c0 = blockIdx.x * 32;
    const int r0 = blockIdx.y * 32;
    const int b  = blockIdx.z;
    const float* S = src + (size_t)b * R * C;
    float* D = dst + (size_t)b * R * C;
    const int tx = threadIdx.x;      // 0..31
    const int ty = threadIdx.y;      // 0..7
#pragma unroll
    for (int s = 0; s < 4; s++) {
        const int r = r0 + ty + 8 * s;
        const int c = c0 + tx;
        if (r < R && c < C) tile[ty + 8 * s][tx] = S[(size_t)r * C + c];
    }
    __syncthreads();
#pragma unroll
    for (int s = 0; s < 4; s++) {
        const int c = c0 + ty + 8 * s;
        const int r = r0 + tx;
        if (c < C && r < R) D[(size_t)c * R + r] = tile[tx][ty + 8 * s];
    }
}

// ---------------------------------------------------------------------------
// Sparse spike GEMM: C[b,t,o] = sum_i Wt[i,o] * S[b,t,i], skipping S==0.
// S: [B,T,K] binary, Wt: [K,O], C: [B,T,O].
// Block: 256 thr (4 waves), o-chunk 128 (2 o's/lane), t-chunk 32 (8 t/wave),
// K staged in 32-row LDS chunks (16 KB -> 8 blocks/CU occupancy cap, was 5
// at 32 KB), weights register-prefetched one chunk ahead, spike values
// prefetched one chunk ahead (svn) so the ballot never waits on a fresh
// global load. Walk: scalar (SALU) ctz on wave-uniform masks, 4-wide
// ds_read_b64 groups + 2-wide + 1-wide tails, 2 v_add per set bit.
// ---------------------------------------------------------------------------
#define KG  32
#define OCN 128
#define TCN 32

// walk one wave-uniform 32-bit mask into one float2 accumulator
#define WALK32(mw, accu)                                                      \
    {                                                                         \
        unsigned int mask_ = (mw);                                            \
        int n_ = __popc(mask_);                                               \
        float ax_ = (accu).x, ay_ = (accu).y;                                 \
        while (n_ >= 4) {                                                     \
            const int j0_ = __builtin_ctz(mask_); mask_ &= mask_ - 1u;        \
            const int j1_ = __builtin_ctz(mask_); mask_ &= mask_ - 1u;        \
            const int j2_ = __builtin_ctz(mask_); mask_ &= mask_ - 1u;        \
            const int j3_ = __builtin_ctz(mask_); mask_ &= mask_ - 1u;        \
            const float2 w0_ = *(const float2*)(&wlane[j0_ * OCN]);           \
            const float2 w1_ = *(const float2*)(&wlane[j1_ * OCN]);           \
            const float2 w2_ = *(const float2*)(&wlane[j2_ * OCN]);           \
            const float2 w3_ = *(const float2*)(&wlane[j3_ * OCN]);           \
            ax_ += w0_.x; ay_ += w0_.y;                                       \
            ax_ += w1_.x; ay_ += w1_.y;                                       \
            ax_ += w2_.x; ay_ += w2_.y;                                       \
            ax_ += w3_.x; ay_ += w3_.y;                                       \
            n_ -= 4;                                                          \
        }                                                                     \
        if (n_ >= 2) {                                                        \
            const int j0_ = __builtin_ctz(mask_); mask_ &= mask_ - 1u;        \
            const int j1_ = __builtin_ctz(mask_); mask_ &= mask_ - 1u;        \
            const float2 w0_ = *(const float2*)(&wlane[j0_ * OCN]);           \
            const float2 w1_ = *(const float2*)(&wlane[j1_ * OCN]);           \
            ax_ += w0_.x; ay_ += w0_.y;                                       \
            ax_ += w1_.x; ay_ += w1_.y;                                       \
            n_ -= 2;                                                          \
        }                                                                     \
        if (n_ > 0) {                                                         \
            const int j0_ = __builtin_ctz(mask_);                             \
            const float2 w0_ = *(const float2*)(&wlane[j0_ * OCN]);           \
            ax_ += w0_.x; ay_ += w0_.y;                                       \
        }                                                                     \
        (accu).x = ax_; (accu).y = ay_;                                       \
    }

__global__ __launch_bounds__(256) void spmm_snn(
    const float* __restrict__ S, const float* __restrict__ Wt,
    float* __restrict__ C, int K, int O, int T)
{
    __shared__ float Wls[KG * OCN];   // 16 KB
    const int tid  = threadIdx.x;
    const int lane = tid & 63;
    const int wv   = tid >> 6;        // 0..3
    const int oc   = blockIdx.x * OCN;
    const int t0   = blockIdx.y * TCN;
    const int b    = blockIdx.z;

    const float* Sb = S + (size_t)b * T * K;
    float* Cb = C + (size_t)b * T * O;

    // weight staging: 32 rows x 128 cols = 16 KB = 256 thr x float4 x 4 iters
    const int srow  = tid >> 5;        // base row (stride 8 over r)
    const int scol4 = (tid & 31) * 4;

    float2 acc[8];
#pragma unroll
    for (int u = 0; u < 8; u++) acc[u] = make_float2(0.f, 0.f);

    const int nkc = (K + KG - 1) / KG;
    float4 wpf[4];

#define LOADW(kc)                                                              \
    {                                                                          \
        const int kb_ = (kc) * KG;                                             \
        _Pragma("unroll")                                                      \
        for (int r = 0; r < 4; r++) {                                          \
            const int k = kb_ + srow + r * 8;                                  \
            const int o = oc + scol4;                                          \
            float4 w = make_float4(0.f, 0.f, 0.f, 0.f);                        \
            if (k < K && o + 3 < O)                                            \
                w = *reinterpret_cast<const float4*>(&Wt[(size_t)k * O + o]);  \
            wpf[r] = w;                                                        \
        }                                                                      \
    }

#define STOREW()                                                               \
    {                                                                          \
        _Pragma("unroll")                                                      \
        for (int r = 0; r < 4; r++)                                            \
            *reinterpret_cast<float4*>(&Wls[(srow + r * 4 * 8 / 4) * OCN + scol4]) = wpf[r]; \
    }
// note: srow + r*8 rows (srow in 0..7, 4 passes cover rows 0..31)
#undef STOREW
#define STOREW()                                                               \
    {                                                                          \
        _Pragma("unroll")                                                      \
        for (int r = 0; r < 4; r++)                                            \
            *reinterpret_cast<float4*>(&Wls[(srow + r * 8) * OCN + scol4]) = wpf[r]; \
    }

    // spike prefetch: lanes 0-31 carry t_even (u=2p), lanes 32-63 t_odd
    // (u=2p+1); k = kbase + (lane&31). Ballot word0 = t_even, word1 = t_odd.
    float sv[4], svn[4];
#define LOADS(kc, dst)                                                         \
    {                                                                          \
        const int kk_ = (kc) * KG + (lane & 31);                               \
        _Pragma("unroll")                                                      \
        for (int p = 0; p < 4; p++) {                                          \
            const int t = t0 + (2 * p + (lane >> 5)) * 4 + wv;                 \
            dst[p] = (t < T && kk_ < K) ? Sb[(size_t)t * K + kk_] : 0.0f;      \
        }                                                                      \
    }

    LOADW(0)
    LOADS(0, sv)
    STOREW()
    __syncthreads();

    // per-lane LDS base: row j's float2 for this lane at float offset j*OCN
    const float* wlane = &Wls[lane * 2];

    for (int kc = 0; kc < nkc; kc++) {
        if (kc + 1 < nkc) {
            LOADW(kc + 1)          // global->reg, lands during the walk
            LOADS(kc + 1, svn)
        }

        unsigned long long mk[4];
#pragma unroll
        for (int p = 0; p < 4; p++) mk[p] = __ballot(sv[p] != 0.0f);

#pragma unroll
        for (int p = 0; p < 4; p++) {
            WALK32((unsigned int)mk[p],         acc[2 * p])      // t0+(2p)*4+wv
            WALK32((unsigned int)(mk[p] >> 32), acc[2 * p + 1])  // t0+(2p+1)*4+wv
        }

        if (kc + 1 < nkc) {
            __syncthreads();       // all waves done reading Wls
            STOREW()
#pragma unroll
            for (int p = 0; p < 4; p++) sv[p] = svn[p];
            __syncthreads();       // Wls chunk kc+1 visible
        }
    }

#pragma unroll
    for (int u = 0; u < 8; u++) {
        const int t = t0 + u * 4 + wv;
        const int o = oc + lane * 2;
        if (t < T && o + 1 < O)               // O even -> pair all-or-nothing
            *reinterpret_cast<float2*>(&Cb[(size_t)t * O + o]) = acc[u];
    }
}

// ---------------------------------------------------------------------------
// LIF in time-major layout, in-place: C[b,t,o] currents -> spikes.
// One thread per (b,o); strided (stride O) column walk with 8-deep unrolled
// prefetch ring (constant indices -> stays in VGPRs). T fixed at 300.
// ---------------------------------------------------------------------------
#define LIF_STEP_S(xval, sval)                                                 \
    {                                                                          \
        const float y = A1 * y1 + A2 * y2 + Bc * (xval); y2 = y1; y1 = y;      \
        const float v = y + bi + r;                                            \
        sval = (v >= 1.0f) ? 1.0f : 0.0f;                                      \
        r = r * EMF - sval;                                                    \
    }

__global__ __launch_bounds__(64) void lif_t(
    float* __restrict__ C, const float* __restrict__ bias,
    const float* __restrict__ a1p, const float* __restrict__ a2p,
    const float* __restrict__ bp, int O)
{
    const int o = blockIdx.x * 64 + threadIdx.x;
    const int b = blockIdx.y;
    if (o >= O) return;
    const float A1 = a1p[0], A2 = a2p[0], Bc = bp[0];
    const float bi = bias[o];
    float* col = C + (size_t)b * 300 * O + o;

    float pf[8];
#pragma unroll
    for (int u = 0; u < 8; u++) pf[u] = col[(size_t)u * O];

    float y1 = 0.f, y2 = 0.f, r = 0.f;
    for (int blk = 0; blk < 37; blk++) {       // t = 0..295
#pragma unroll
        for (int u = 0; u < 8; u++) {
            const int t = blk * 8 + u;
            const float x = pf[u];
            if (t + 8 < 300) pf[u] = col[(size_t)(t + 8) * O];
            float s;
            LIF_STEP_S(x, s)
            col[(size_t)t * O] = s;
        }
    }
#pragma unroll
    for (int u = 0; u < 4; u++) {              // t = 296..299
        const float x = pf[u];
        float s;
        LIF_STEP_S(x, s)
        col[(size_t)(296 + u) * O] = s;
    }
}

// ---------------------------------------------------------------------------
// Layer-4 LIF + fixed output dual-exp IIR. C: currents->spikes (in place),
// F: filtered output. Both [B,T,O], O=300.
// ---------------------------------------------------------------------------
__global__ __launch_bounds__(64) void lif4_t(
    float* __restrict__ C, float* __restrict__ F,
    const float* __restrict__ bias,
    const float* __restrict__ a1p, const float* __restrict__ a2p,
    const float* __restrict__ bp, int O)
{
    const int o = blockIdx.x * 64 + threadIdx.x;
    const int b = blockIdx.y;
    if (o >= O) return;
    const float A1 = a1p[0], A2 = a2p[0], Bc = bp[0];
    const float bi = bias[o];
    float* col  = C + (size_t)b * 300 * O + o;
    float* fcol = F + (size_t)b * 300 * O + o;

    float pf[8];
#pragma unroll
    for (int u = 0; u < 8; u++) pf[u] = col[(size_t)u * O];

    float y1 = 0.f, y2 = 0.f, r = 0.f;
    float z1 = 0.f, z2 = 0.f;
    for (int blk = 0; blk < 37; blk++) {
#pragma unroll
        for (int u = 0; u < 8; u++) {
            const int t = blk * 8 + u;
            const float x = pf[u];
            if (t + 8 < 300) pf[u] = col[(size_t)(t + 8) * O];
            float s;
            LIF_STEP_S(x, s)
            const float z = A1C * z1 + A2C * z2 + BC * s; z2 = z1; z1 = z;
            col[(size_t)t * O]  = s;
            fcol[(size_t)t * O] = z;
        }
    }
#pragma unroll
    for (int u = 0; u < 4; u++) {
        const int t = 296 + u;
        const float x = pf[u];
        float s;
        LIF_STEP_S(x, s)
        const float z = A1C * z1 + A2C * z2 + BC * s; z2 = z1; z1 = z;
        col[(size_t)t * O]  = s;
        fcol[(size_t)t * O] = z;
    }
}

// ---------------------------------------------------------------------------
extern "C" void kernel_launch(void* const* d_in, const int* in_sizes, int n_in,
                              void* d_out, int out_size, void* d_ws, size_t ws_size,
                              hipStream_t stream)
{
    const float* inputs = (const float*)d_in[0];           // [64,300,300] binary
    const float* a1_1 = (const float*)d_in[1];
    const float* a2_1 = (const float*)d_in[2];
    const float* b_1  = (const float*)d_in[3];
    const float* W1   = (const float*)d_in[4];             // [500,300]
    const float* bias1= (const float*)d_in[5];
    const float* a1_2 = (const float*)d_in[6];
    const float* a2_2 = (const float*)d_in[7];
    const float* b_2  = (const float*)d_in[8];
    const float* W2   = (const float*)d_in[9];             // [200,500]
    const float* bias2= (const float*)d_in[10];
    const float* a1_3 = (const float*)d_in[11];
    const float* a2_3 = (const float*)d_in[12];
    const float* b_3  = (const float*)d_in[13];
    const float* W3   = (const float*)d_in[14];            // [500,200]
    const float* bias3= (const float*)d_in[15];
    const float* a1_4 = (const float*)d_in[16];
    const float* a2_4 = (const float*)d_in[17];
    const float* b_4  = (const float*)d_in[18];
    const float* W4   = (const float*)d_in[19];            // [300,500]
    const float* bias4= (const float*)d_in[20];

    const int B = 64, T = 300;

    // Workspace (proven size 53.76 MB): c1 = 9.6M floats, c2 = 3.84M floats.
    float* ws = (float*)d_ws;
    float* c1 = ws;                 // [B,T,500]; later filt_tmp [B,T,300]
    float* c2 = ws + 9600000;       // [B,T,200]

    // d_out regions double as scratch until the final transposes:
    // region1 [0..5.76M): Wt1..4 (500K floats), later final s4 [B,O,T]
    // region2 [5.76M..11.52M): inputT/c4/s4_tmp [B,T,300], later final filt
    float* out = (float*)d_out;
    float* reg1 = out;
    float* reg2 = out + 5760000;
    float* Wt1 = reg1;              // [300,500] = 150000
    float* Wt2 = reg1 + 150000;     // [500,200] = 100000
    float* Wt3 = reg1 + 250000;     // [200,500] = 100000
    float* Wt4 = reg1 + 350000;     // [500,300] = 150000

    const dim3 tb(32, 8);

    // Weight transposes W[O,K] -> Wt[K,O]
    transpose_rc<<<dim3(10, 16, 1), tb, 0, stream>>>(W1, Wt1, 500, 300);
    transpose_rc<<<dim3(16,  7, 1), tb, 0, stream>>>(W2, Wt2, 200, 500);
    transpose_rc<<<dim3( 7, 16, 1), tb, 0, stream>>>(W3, Wt3, 500, 200);
    transpose_rc<<<dim3(16, 10, 1), tb, 0, stream>>>(W4, Wt4, 300, 500);
    // Input spikes [B,IN,T] -> [B,T,IN]
    transpose_rc<<<dim3(10, 10, B), tb, 0, stream>>>(inputs, reg2, 300, 300);

    // Layer 1: 300 -> 500
    spmm_snn<<<dim3(4, 10, B), 256, 0, stream>>>(reg2, Wt1, c1, 300, 500, T);
    lif_t<<<dim3(8, B), 64, 0, stream>>>(c1, bias1, a1_1, a2_1, b_1, 500);
    // Layer 2: 500 -> 200
    spmm_snn<<<dim3(2, 10, B), 256, 0, stream>>>(c1, Wt2, c2, 500, 200, T);
    lif_t<<<dim3(4, B), 64, 0, stream>>>(c2, bias2, a1_2, a2_2, b_2, 200);
    // Layer 3: 200 -> 500 (write into c1; s1 dead)
    spmm_snn<<<dim3(4, 10, B), 256, 0, stream>>>(c2, Wt3, c1, 200, 500, T);
    lif_t<<<dim3(8, B), 64, 0, stream>>>(c1, bias3, a1_3, a2_3, b_3, 500);
    // Layer 4: 500 -> 300 into reg2 (inputT dead); LIF+filter, filt_tmp -> c1
    spmm_snn<<<dim3(3, 10, B), 256, 0, stream>>>(c1, Wt4, reg2, 500, 300, T);
    lif4_t<<<dim3(5, B), 64, 0, stream>>>(reg2, c1, bias4, a1_4, a2_4, b_4, 300);

    // Final transposes [B,T,O] -> [B,O,T]: s4 first (frees reg2), then filt.
    transpose_rc<<<dim3(10, 10, B), tb, 0, stream>>>(reg2, reg1, 300, 300);
    transpose_rc<<<dim3(10, 10, B), tb, 0, stream>>>(c1, reg2, 300, 300);
}